// Round 14
// baseline (3886.135 us; speedup 1.0000x reference)
//
#include <hip/hip_runtime.h>
#include <hip/hip_fp16.h>
#include <math.h>

#define BB 128
#define FF 256
#define NN 2000
#define SW 8      // stripes per batch
#define SC 256    // cols per stripe

// Diagnostic repetition factors (idempotent reps; revert to 1 after reading counters)
#define REP_CONV 4
#define REP_PREP 64
#define REP_ATTN 16
#define REP_DENSE 64
#define REP_LOG 16

typedef float f32x4 __attribute__((ext_vector_type(4)));
union H8 { f32x4 v; __half2 h[4]; };

__device__ __forceinline__ float sel8(f32x4 a, f32x4 b, int e) {
    float v;
    switch (e) {
        case 0: v = a.x; break; case 1: v = a.y; break;
        case 2: v = a.z; break; case 3: v = a.w; break;
        case 4: v = b.x; break; case 5: v = b.y; break;
        case 6: v = b.z; break; default: v = b.w; break;
    }
    return v;
}

// -------- K1: x -> fp16, row max, last/current column extraction --------
__global__ __launch_bounds__(256) void k_convmax(const float* __restrict__ x,
                                                 const int* __restrict__ lc,
                                                 __half* __restrict__ xh,
                                                 float* __restrict__ glb,
                                                 float* __restrict__ xg) {
    int row  = (blockIdx.x << 2) | (threadIdx.x >> 6);
    int lane = threadIdx.x & 63;
    int b    = row >> 8;
    const int c0 = lc[2 * b], c1 = lc[2 * b + 1];
    const int i0 = c0 >> 3, e0 = c0 & 7;
    const int i1 = c1 >> 3, e1 = c1 & 7;
    const f32x4* src = (const f32x4*)(x + (size_t)row * NN);
    f32x4*       dst = (f32x4*)(xh + (size_t)row * NN);
#pragma unroll 1
    for (int rep = 0; rep < REP_CONV; ++rep) {
        float m = -INFINITY;
        for (int i = lane; i < 250; i += 64) {
            f32x4 a = __builtin_nontemporal_load(src + 2 * i);
            f32x4 q = __builtin_nontemporal_load(src + 2 * i + 1);
            m = fmaxf(m, fmaxf(fmaxf(a.x, a.y), fmaxf(a.z, a.w)));
            m = fmaxf(m, fmaxf(fmaxf(q.x, q.y), fmaxf(q.z, q.w)));
            if (i == i0) xg[row * 2]     = sel8(a, q, e0);
            if (i == i1) xg[row * 2 + 1] = sel8(a, q, e1);
            H8 o;
            o.h[0] = __floats2half2_rn(a.x, a.y);
            o.h[1] = __floats2half2_rn(a.z, a.w);
            o.h[2] = __floats2half2_rn(q.x, q.y);
            o.h[3] = __floats2half2_rn(q.z, q.w);
            dst[i] = o.v;
        }
#pragma unroll
        for (int off = 32; off; off >>= 1) m = fmaxf(m, __shfl_xor(m, off));
        if (!lane) glb[row] = m;
        asm volatile("" ::: "memory");
    }
}

// -------- K2: per-batch dense prep -> cK[b,f], cK0[b] --------
__global__ __launch_bounds__(256) void k_prep(
    const float* __restrict__ xg, const float* __restrict__ glb,
    const float* __restrict__ Wg, const float* __restrict__ bg,
    const float* __restrict__ Wnode, const float* __restrict__ bnode,
    const float* __restrict__ Wlc, const float* __restrict__ blc,
    float* __restrict__ cK, float* __restrict__ cK0)
{
    int b = blockIdx.x;
    int f = threadIdx.x;
    __shared__ float s_glb[FF], s_ctx[2 * FF], s_cQ[FF], s_red[FF];
#pragma unroll 1
    for (int rep = 0; rep < REP_PREP; ++rep) {
        s_glb[f] = glb[b * FF + f];
        float2 g2 = ((const float2*)xg)[b * FF + f];
        s_ctx[f]      = g2.x;
        s_ctx[FF + f] = g2.y;
        __syncthreads();
        const float* wg = Wg + (size_t)f * FF;
        float q0 = 0, q1 = 0, q2 = 0, q3 = 0;
        for (int j = 0; j < FF; j += 4) {
            q0 = fmaf(wg[j],     s_glb[j],     q0);
            q1 = fmaf(wg[j + 1], s_glb[j + 1], q1);
            q2 = fmaf(wg[j + 2], s_glb[j + 2], q2);
            q3 = fmaf(wg[j + 3], s_glb[j + 3], q3);
        }
        const float* wl = Wlc + (size_t)f * 2 * FF;
        for (int j = 0; j < 2 * FF; j += 4) {
            q0 = fmaf(wl[j],     s_ctx[j],     q0);
            q1 = fmaf(wl[j + 1], s_ctx[j + 1], q1);
            q2 = fmaf(wl[j + 2], s_ctx[j + 2], q2);
            q3 = fmaf(wl[j + 3], s_ctx[j + 3], q3);
        }
        float cq = bg[f] + blc[f] + ((q0 + q1) + (q2 + q3));
        s_cQ[f]  = cq;
        s_red[f] = cq * bnode[f];
        __syncthreads();
        float c0 = 0, c1 = 0;
        for (int g = 0; g < FF; g += 2) {
            c0 = fmaf(s_cQ[g],     Wnode[(size_t)g * FF + f],       c0);
            c1 = fmaf(s_cQ[g + 1], Wnode[(size_t)(g + 1) * FF + f], c1);
        }
        cK[b * FF + f] = c0 + c1;
        for (int s = 128; s > 0; s >>= 1) {
            if (f < s) s_red[f] += s_red[f + s];
            __syncthreads();
        }
        if (f == 0) cK0[b] = s_red[0];
        __syncthreads();
        asm volatile("" ::: "memory");
    }
}

// -------- K3: fused attn, LDS tile with XOR bank swizzle --------
__global__ __launch_bounds__(512) void k_attn(
    const __half* __restrict__ xh,
    const float* __restrict__ cK, const float* __restrict__ cK0,
    float* __restrict__ y_part, float* __restrict__ m_part,
    float* __restrict__ s_part)
{
    int b = blockIdx.x >> 3, st = blockIdx.x & 7;
    int tid = threadIdx.x, w = tid >> 6, lane = tid & 63;
    int par = lane >> 5, chunk = lane & 31;
    __shared__ __half tile[FF][SC];
    __shared__ float s_u[8][SC];
    __shared__ float s_p[SC];
    __shared__ float s_cK[FF];
    __shared__ float s_red[8], s_red2[8];
    if (tid < FF) s_cK[tid] = cK[b * FF + tid];
    __syncthreads();

    int colbase = (st << 8) + (chunk << 3);
    bool cvalid = colbase < NN;
    const __half* base = xh + ((size_t)(b * FF) + (w << 5) + par) * NN + colbase;

#pragma unroll 1
    for (int rep = 0; rep < REP_ATTN; ++rep) {
        // ---- pass 1 ----
        float up0 = 0, up1 = 0, up2 = 0, up3 = 0, up4 = 0, up5 = 0, up6 = 0, up7 = 0;
#pragma unroll
        for (int g = 0; g < 4; ++g) {
            f32x4 hv[4];
#pragma unroll
            for (int r = 0; r < 4; ++r) {
                if (cvalid) hv[r] = *(const f32x4*)(base + (size_t)((g << 3) + (r << 1)) * NN);
                else        hv[r] = (f32x4){0.f, 0.f, 0.f, 0.f};
            }
#pragma unroll
            for (int r = 0; r < 4; ++r) {
                int row = (w << 5) + par + (g << 3) + (r << 1);
                *(f32x4*)&tile[row][(chunk ^ (row & 7)) << 3] = hv[r];
                H8 u; u.v = hv[r];
                float c = s_cK[row];
                float2 q0 = __half22float2(u.h[0]);
                float2 q1 = __half22float2(u.h[1]);
                float2 q2 = __half22float2(u.h[2]);
                float2 q3 = __half22float2(u.h[3]);
                up0 = fmaf(c, q0.x, up0); up1 = fmaf(c, q0.y, up1);
                up2 = fmaf(c, q1.x, up2); up3 = fmaf(c, q1.y, up3);
                up4 = fmaf(c, q2.x, up4); up5 = fmaf(c, q2.y, up5);
                up6 = fmaf(c, q3.x, up6); up7 = fmaf(c, q3.y, up7);
            }
        }
        up0 += __shfl_xor(up0, 32); up1 += __shfl_xor(up1, 32);
        up2 += __shfl_xor(up2, 32); up3 += __shfl_xor(up3, 32);
        up4 += __shfl_xor(up4, 32); up5 += __shfl_xor(up5, 32);
        up6 += __shfl_xor(up6, 32); up7 += __shfl_xor(up7, 32);
        if (!par) {
            f32x4 v0 = {up0, up1, up2, up3}, v1 = {up4, up5, up6, up7};
            *(f32x4*)&s_u[w][chunk << 3]       = v0;
            *(f32x4*)&s_u[w][(chunk << 3) + 4] = v1;
        }
        __syncthreads();

        // ---- stripe softmax ----
        const float scale = 0.0625f;
        float uu = -INFINITY;
        if (tid < SC) {
            int col = (st << 8) + tid;
            if (col < NN) {
                float usum = 0.f;
#pragma unroll
                for (int ww = 0; ww < 8; ++ww) usum += s_u[ww][tid];
                uu = (usum + cK0[b]) * scale;
            }
        }
        float m = uu;
#pragma unroll
        for (int off = 32; off; off >>= 1) m = fmaxf(m, __shfl_xor(m, off));
        if (!lane && w < 4) s_red[w] = m;
        __syncthreads();
        float M = fmaxf(fmaxf(s_red[0], s_red[1]), fmaxf(s_red[2], s_red[3]));
        float e = (uu > -INFINITY) ? __expf(uu - M) : 0.f;
        if (tid < SC) s_p[tid] = e;
        float ssum = e;
#pragma unroll
        for (int off = 32; off; off >>= 1) ssum += __shfl_xor(ssum, off);
        if (!lane && w < 4) s_red2[w] = ssum;
        __syncthreads();
        if (!tid) {
            m_part[(b << 3) + st] = M;
            s_part[(b << 3) + st] = s_red2[0] + s_red2[1] + s_red2[2] + s_red2[3];
        }

        // ---- pass 2 ----
        f32x4 pv0 = *(const f32x4*)&s_p[chunk << 3];
        f32x4 pv1 = *(const f32x4*)&s_p[(chunk << 3) + 4];
        float acc[16];
#pragma unroll
        for (int k = 0; k < 16; ++k) {
            int row = (w << 5) + par + (k << 1);
            H8 u; u.v = *(const f32x4*)&tile[row][(chunk ^ (row & 7)) << 3];
            float2 q0 = __half22float2(u.h[0]);
            float2 q1 = __half22float2(u.h[1]);
            float2 q2 = __half22float2(u.h[2]);
            float2 q3 = __half22float2(u.h[3]);
            float a = 0.f;
            a = fmaf(pv0.x, q0.x, a); a = fmaf(pv0.y, q0.y, a);
            a = fmaf(pv0.z, q1.x, a); a = fmaf(pv0.w, q1.y, a);
            a = fmaf(pv1.x, q2.x, a); a = fmaf(pv1.y, q2.y, a);
            a = fmaf(pv1.z, q3.x, a); a = fmaf(pv1.w, q3.y, a);
            acc[k] = a;
        }
        __syncthreads();
        float* tbuf = (float*)&tile[0][0];
#pragma unroll
        for (int k = 0; k < 16; ++k)
            tbuf[(w << 10) + ((par + (k << 1)) << 5) + chunk] = acc[k];
        __syncthreads();
        {
            int row = tid >> 1, half = tid & 1;
            const float* srcp = tbuf + ((row >> 5) << 10) + ((row & 31) << 5) + (half << 4);
            f32x4 a0 = *(const f32x4*)srcp;
            f32x4 a1 = *(const f32x4*)(srcp + 4);
            f32x4 a2 = *(const f32x4*)(srcp + 8);
            f32x4 a3 = *(const f32x4*)(srcp + 12);
            float sm = ((a0.x + a0.y) + (a0.z + a0.w)) + ((a1.x + a1.y) + (a1.z + a1.w)) +
                       ((a2.x + a2.y) + (a2.z + a2.w)) + ((a3.x + a3.y) + (a3.z + a3.w));
            sm += __shfl_xor(sm, 1);
            if (!half) y_part[(size_t)((b << 3) + st) * FF + row] = sm;
        }
        __syncthreads();
        asm volatile("" ::: "memory");
    }
}

// -------- K4: combine 8 stripe partials -> y -> dense chain -> cL, cL0 --------
__global__ __launch_bounds__(256) void k_dense(
    const float* __restrict__ y_part, const float* __restrict__ m_part,
    const float* __restrict__ s_part,
    const float* __restrict__ Wnode, const float* __restrict__ bnode,
    const float* __restrict__ Wproj, const float* __restrict__ bproj,
    float* __restrict__ cL, float* __restrict__ cL0)
{
    int b = blockIdx.x;
    int f = threadIdx.x;
    int wid = f >> 6, lane = f & 63;
    __shared__ float s_y[FF], s_v[FF], s_red[4];
#pragma unroll 1
    for (int rep = 0; rep < REP_DENSE; ++rep) {
        float M = -INFINITY;
#pragma unroll
        for (int s = 0; s < 8; ++s) M = fmaxf(M, m_part[(b << 3) + s]);
        float S = 0.f, wgt[8];
#pragma unroll
        for (int s = 0; s < 8; ++s) {
            wgt[s] = __expf(m_part[(b << 3) + s] - M);
            S = fmaf(wgt[s], s_part[(b << 3) + s], S);
        }
        float invS = 1.0f / S;
        float acc = 0.f;
#pragma unroll
        for (int s = 0; s < 8; ++s)
            acc = fmaf(wgt[s], y_part[(size_t)((b << 3) + s) * FF + f], acc);
        s_y[f] = acc * invS;
        __syncthreads();

        const float* wv = Wnode + (size_t)(FF + f) * FF;
        float a0 = 0, a1 = 0, a2 = 0, a3 = 0;
        for (int j = 0; j < FF; j += 4) {
            a0 = fmaf(wv[j],     s_y[j],     a0);
            a1 = fmaf(wv[j + 1], s_y[j + 1], a1);
            a2 = fmaf(wv[j + 2], s_y[j + 2], a2);
            a3 = fmaf(wv[j + 3], s_y[j + 3], a3);
        }
        s_v[f] = bnode[FF + f] + ((a0 + a1) + (a2 + a3));
        __syncthreads();
        const float* wp = Wproj + (size_t)f * FF;
        a0 = 0; a1 = 0; a2 = 0; a3 = 0;
        for (int j = 0; j < FF; j += 4) {
            a0 = fmaf(wp[j],     s_v[j],     a0);
            a1 = fmaf(wp[j + 1], s_v[j + 1], a1);
            a2 = fmaf(wp[j + 2], s_v[j + 2], a2);
            a3 = fmaf(wp[j + 3], s_v[j + 3], a3);
        }
        float nc2 = bproj[f] + ((a0 + a1) + (a2 + a3));
        __syncthreads();
        s_v[f] = nc2;
        __syncthreads();
        float c0 = 0, c1 = 0;
        for (int g = 0; g < FF; g += 2) {
            c0 = fmaf(s_v[g],     Wnode[(size_t)(2 * FF + g) * FF + f],     c0);
            c1 = fmaf(s_v[g + 1], Wnode[(size_t)(2 * FF + g + 1) * FF + f], c1);
        }
        cL[b * FF + f] = c0 + c1;
        float t = nc2 * bnode[2 * FF + f];
#pragma unroll
        for (int off = 32; off; off >>= 1) t += __shfl_xor(t, off);
        if (!lane) s_red[wid] = t;
        __syncthreads();
        if (!f) cL0[b] = s_red[0] + s_red[1] + s_red[2] + s_red[3];
        __syncthreads();
        asm volatile("" ::: "memory");
    }
}

// -------- K5: logits + tanh --------
__global__ __launch_bounds__(512) void k_logits(const __half* __restrict__ xh,
                                                const float* __restrict__ cL,
                                                const float* __restrict__ cL0,
                                                float* __restrict__ out)
{
    int b = blockIdx.x >> 3, st = blockIdx.x & 7;
    int tid = threadIdx.x, w = tid >> 6, lane = tid & 63;
    int par = lane >> 5, chunk = lane & 31;
    __shared__ float s_cL[FF];
    __shared__ float s_acc[8][SC];
    if (tid < FF) s_cL[tid] = cL[b * FF + tid];
    __syncthreads();

    int colbase = (st << 8) + (chunk << 3);
    bool cvalid = colbase < NN;
    const __half* base = xh + ((size_t)(b * FF) + (w << 5) + par) * NN + colbase;
#pragma unroll 1
    for (int rep = 0; rep < REP_LOG; ++rep) {
        float up0 = 0, up1 = 0, up2 = 0, up3 = 0, up4 = 0, up5 = 0, up6 = 0, up7 = 0;
        if (cvalid) {
#pragma unroll
            for (int g = 0; g < 4; ++g) {
                f32x4 hv[4];
#pragma unroll
                for (int r = 0; r < 4; ++r)
                    hv[r] = *(const f32x4*)(base + (size_t)((g << 3) + (r << 1)) * NN);
#pragma unroll
                for (int r = 0; r < 4; ++r) {
                    int row = (w << 5) + par + (g << 3) + (r << 1);
                    H8 u; u.v = hv[r];
                    float c = s_cL[row];
                    float2 q0 = __half22float2(u.h[0]);
                    float2 q1 = __half22float2(u.h[1]);
                    float2 q2 = __half22float2(u.h[2]);
                    float2 q3 = __half22float2(u.h[3]);
                    up0 = fmaf(c, q0.x, up0); up1 = fmaf(c, q0.y, up1);
                    up2 = fmaf(c, q1.x, up2); up3 = fmaf(c, q1.y, up3);
                    up4 = fmaf(c, q2.x, up4); up5 = fmaf(c, q2.y, up5);
                    up6 = fmaf(c, q3.x, up6); up7 = fmaf(c, q3.y, up7);
                }
            }
        }
        up0 += __shfl_xor(up0, 32); up1 += __shfl_xor(up1, 32);
        up2 += __shfl_xor(up2, 32); up3 += __shfl_xor(up3, 32);
        up4 += __shfl_xor(up4, 32); up5 += __shfl_xor(up5, 32);
        up6 += __shfl_xor(up6, 32); up7 += __shfl_xor(up7, 32);
        if (!par) {
            f32x4 v0 = {up0, up1, up2, up3}, v1 = {up4, up5, up6, up7};
            *(f32x4*)&s_acc[w][chunk << 3]       = v0;
            *(f32x4*)&s_acc[w][(chunk << 3) + 4] = v1;
        }
        __syncthreads();
        if (tid < SC) {
            int col = (st << 8) + tid;
            if (col < NN) {
                float t = 0.f;
#pragma unroll
                for (int ww = 0; ww < 8; ++ww) t += s_acc[ww][tid];
                out[(size_t)b * NN + col] = tanhf((t + cL0[b]) * 0.0625f) * 10.f;
            }
        }
        __syncthreads();
        asm volatile("" ::: "memory");
    }
}

extern "C" void kernel_launch(void* const* d_in, const int* in_sizes, int n_in,
                              void* d_out, int out_size, void* d_ws, size_t ws_size,
                              hipStream_t stream) {
    const float* x     = (const float*)d_in[0];
    const int*   lc    = (const int*)d_in[1];
    const float* Wg    = (const float*)d_in[2];
    const float* bg    = (const float*)d_in[3];
    const float* Wnode = (const float*)d_in[4];
    const float* bnode = (const float*)d_in[5];
    const float* Wlc   = (const float*)d_in[6];
    const float* blc   = (const float*)d_in[7];
    const float* Wproj = (const float*)d_in[8];
    const float* bproj = (const float*)d_in[9];
    float* out = (float*)d_out;

    float* ws     = (float*)d_ws;
    float* glb    = ws + 0;          // B*F
    float* xg     = ws + 32768;      // B*F*2
    float* cK     = ws + 98304;      // B*F
    float* cK0    = ws + 131072;     // B
    float* m_part = ws + 132096;     // B*8
    float* s_part = ws + 134144;     // B*8
    float* cL     = ws + 136192;     // B*F
    float* cL0    = ws + 168960;     // B
    float* y_part = ws + 169984;     // B*8*F
    __half* xh    = (__half*)(ws + (2 << 20));  // 131 MB at 8 MB offset

    k_convmax<<<BB * FF / 4, 256, 0, stream>>>(x, lc, xh, glb, xg);
    k_prep   <<<BB, 256, 0, stream>>>(xg, glb, Wg, bg, Wnode, bnode, Wlc, blc, cK, cK0);
    k_attn   <<<BB * SW, 512, 0, stream>>>(xh, cK, cK0, y_part, m_part, s_part);
    k_dense  <<<BB, 256, 0, stream>>>(y_part, m_part, s_part, Wnode, bnode, Wproj, bproj, cL, cL0);
    k_logits <<<BB * SW, 512, 0, stream>>>(xh, cL, cL0, out);
}

// Round 15
// 182.792 us; speedup vs baseline: 21.2599x; 21.2599x over previous
//
#include <hip/hip_runtime.h>
#include <hip/hip_fp16.h>
#include <math.h>

#define BB 128
#define FF 256
#define NN 2000
#define SW 8      // stripes per batch
#define SC 256    // cols per stripe

typedef float f32x4 __attribute__((ext_vector_type(4)));
union H8 { f32x4 v; __half2 h[4]; };

__device__ __forceinline__ float sel8(f32x4 a, f32x4 b, int e) {
    float v;
    switch (e) {
        case 0: v = a.x; break; case 1: v = a.y; break;
        case 2: v = a.z; break; case 3: v = a.w; break;
        case 4: v = b.x; break; case 5: v = b.y; break;
        case 6: v = b.z; break; default: v = b.w; break;
    }
    return v;
}

__device__ __forceinline__ float dot4(f32x4 a, f32x4 b) {
    float s = a.x * b.x;
    s = fmaf(a.y, b.y, s);
    s = fmaf(a.z, b.z, s);
    s = fmaf(a.w, b.w, s);
    return s;
}

// -------- K1: x -> fp16, row max, last/current column extraction --------
__global__ __launch_bounds__(256) void k_convmax(const float* __restrict__ x,
                                                 const int* __restrict__ lc,
                                                 __half* __restrict__ xh,
                                                 float* __restrict__ glb,
                                                 float* __restrict__ xg) {
    int row  = (blockIdx.x << 2) | (threadIdx.x >> 6);
    int lane = threadIdx.x & 63;
    int b    = row >> 8;
    const int c0 = lc[2 * b], c1 = lc[2 * b + 1];
    const int i0 = c0 >> 3, e0 = c0 & 7;
    const int i1 = c1 >> 3, e1 = c1 & 7;
    const f32x4* src = (const f32x4*)(x + (size_t)row * NN);
    f32x4*       dst = (f32x4*)(xh + (size_t)row * NN);
    float m = -INFINITY;
    for (int i = lane; i < 250; i += 64) {
        f32x4 a = __builtin_nontemporal_load(src + 2 * i);
        f32x4 q = __builtin_nontemporal_load(src + 2 * i + 1);
        m = fmaxf(m, fmaxf(fmaxf(a.x, a.y), fmaxf(a.z, a.w)));
        m = fmaxf(m, fmaxf(fmaxf(q.x, q.y), fmaxf(q.z, q.w)));
        if (i == i0) xg[row * 2]     = sel8(a, q, e0);
        if (i == i1) xg[row * 2 + 1] = sel8(a, q, e1);
        H8 o;
        o.h[0] = __floats2half2_rn(a.x, a.y);
        o.h[1] = __floats2half2_rn(a.z, a.w);
        o.h[2] = __floats2half2_rn(q.x, q.y);
        o.h[3] = __floats2half2_rn(q.z, q.w);
        dst[i] = o.v;
    }
#pragma unroll
    for (int off = 32; off; off >>= 1) m = fmaxf(m, __shfl_xor(m, off));
    if (!lane) glb[row] = m;
}

// -------- K2: prep, wave-per-row coalesced matvecs --------
__global__ __launch_bounds__(256) void k_prep(
    const float* __restrict__ xg, const float* __restrict__ glb,
    const float* __restrict__ Wg, const float* __restrict__ bg,
    const float* __restrict__ Wnode, const float* __restrict__ bnode,
    const float* __restrict__ Wlc, const float* __restrict__ blc,
    float* __restrict__ cK, float* __restrict__ cK0)
{
    int b = blockIdx.x, tid = threadIdx.x, w = tid >> 6, lane = tid & 63;
    __shared__ float s_glb[FF], s_ctx[2 * FF], s_cQ[FF], s_bias[FF], s_red[FF];
    s_glb[tid] = glb[b * FF + tid];
    float2 g2 = ((const float2*)xg)[b * FF + tid];
    s_ctx[tid]      = g2.x;
    s_ctx[FF + tid] = g2.y;
    s_bias[tid] = bg[tid] + blc[tid];
    __syncthreads();

    f32x4 gv  = *(const f32x4*)&s_glb[lane << 2];
    f32x4 c0v = *(const f32x4*)&s_ctx[lane << 3];
    f32x4 c1v = *(const f32x4*)&s_ctx[(lane << 3) + 4];

    // cq: wave-per-row, 4 rows in flight
    for (int k = 0; k < 64; k += 4) {
        float p0, p1, p2, p3;
        {
            int fb = (w << 6) + k;
            f32x4 wg0 = *(const f32x4*)(Wg + (size_t)fb * FF + (lane << 2));
            f32x4 wg1 = *(const f32x4*)(Wg + (size_t)(fb + 1) * FF + (lane << 2));
            f32x4 wg2 = *(const f32x4*)(Wg + (size_t)(fb + 2) * FF + (lane << 2));
            f32x4 wg3 = *(const f32x4*)(Wg + (size_t)(fb + 3) * FF + (lane << 2));
            f32x4 wa0 = *(const f32x4*)(Wlc + (size_t)fb * 2 * FF + (lane << 3));
            f32x4 wb0 = *(const f32x4*)(Wlc + (size_t)fb * 2 * FF + (lane << 3) + 4);
            f32x4 wa1 = *(const f32x4*)(Wlc + (size_t)(fb + 1) * 2 * FF + (lane << 3));
            f32x4 wb1 = *(const f32x4*)(Wlc + (size_t)(fb + 1) * 2 * FF + (lane << 3) + 4);
            f32x4 wa2 = *(const f32x4*)(Wlc + (size_t)(fb + 2) * 2 * FF + (lane << 3));
            f32x4 wb2 = *(const f32x4*)(Wlc + (size_t)(fb + 2) * 2 * FF + (lane << 3) + 4);
            f32x4 wa3 = *(const f32x4*)(Wlc + (size_t)(fb + 3) * 2 * FF + (lane << 3));
            f32x4 wb3 = *(const f32x4*)(Wlc + (size_t)(fb + 3) * 2 * FF + (lane << 3) + 4);
            p0 = dot4(wg0, gv) + dot4(wa0, c0v) + dot4(wb0, c1v);
            p1 = dot4(wg1, gv) + dot4(wa1, c0v) + dot4(wb1, c1v);
            p2 = dot4(wg2, gv) + dot4(wa2, c0v) + dot4(wb2, c1v);
            p3 = dot4(wg3, gv) + dot4(wa3, c0v) + dot4(wb3, c1v);
        }
#pragma unroll
        for (int off = 32; off; off >>= 1) {
            p0 += __shfl_xor(p0, off);
            p1 += __shfl_xor(p1, off);
            p2 += __shfl_xor(p2, off);
            p3 += __shfl_xor(p3, off);
        }
        if (lane == 0) {
            int fb = (w << 6) + k;
            s_cQ[fb]     = p0 + s_bias[fb];
            s_cQ[fb + 1] = p1 + s_bias[fb + 1];
            s_cQ[fb + 2] = p2 + s_bias[fb + 2];
            s_cQ[fb + 3] = p3 + s_bias[fb + 3];
        }
    }
    __syncthreads();

    // cK: column-coalesced, 8-deep
    {
        float a0 = 0, a1 = 0, a2 = 0, a3 = 0, a4 = 0, a5 = 0, a6 = 0, a7 = 0;
        for (int g = 0; g < FF; g += 8) {
            float w0 = Wnode[(size_t)(g + 0) * FF + tid];
            float w1 = Wnode[(size_t)(g + 1) * FF + tid];
            float w2 = Wnode[(size_t)(g + 2) * FF + tid];
            float w3 = Wnode[(size_t)(g + 3) * FF + tid];
            float w4 = Wnode[(size_t)(g + 4) * FF + tid];
            float w5 = Wnode[(size_t)(g + 5) * FF + tid];
            float w6 = Wnode[(size_t)(g + 6) * FF + tid];
            float w7 = Wnode[(size_t)(g + 7) * FF + tid];
            a0 = fmaf(s_cQ[g + 0], w0, a0); a1 = fmaf(s_cQ[g + 1], w1, a1);
            a2 = fmaf(s_cQ[g + 2], w2, a2); a3 = fmaf(s_cQ[g + 3], w3, a3);
            a4 = fmaf(s_cQ[g + 4], w4, a4); a5 = fmaf(s_cQ[g + 5], w5, a5);
            a6 = fmaf(s_cQ[g + 6], w6, a6); a7 = fmaf(s_cQ[g + 7], w7, a7);
        }
        cK[b * FF + tid] = ((a0 + a1) + (a2 + a3)) + ((a4 + a5) + (a6 + a7));
    }
    // cK0
    s_red[tid] = s_cQ[tid] * bnode[tid];
    __syncthreads();
    for (int s = 128; s > 0; s >>= 1) {
        if (tid < s) s_red[tid] += s_red[tid + s];
        __syncthreads();
    }
    if (tid == 0) cK0[b] = s_red[0];
}

// -------- K3: fused attn, LDS tile with XOR bank swizzle (r10 best) --------
__global__ __launch_bounds__(512) void k_attn(
    const __half* __restrict__ xh,
    const float* __restrict__ cK, const float* __restrict__ cK0,
    float* __restrict__ y_part, float* __restrict__ m_part,
    float* __restrict__ s_part)
{
    int b = blockIdx.x >> 3, st = blockIdx.x & 7;
    int tid = threadIdx.x, w = tid >> 6, lane = tid & 63;
    int par = lane >> 5, chunk = lane & 31;
    __shared__ __half tile[FF][SC];
    __shared__ float s_u[8][SC];
    __shared__ float s_p[SC];
    __shared__ float s_cK[FF];
    __shared__ float s_red[8], s_red2[8];
    if (tid < FF) s_cK[tid] = cK[b * FF + tid];
    __syncthreads();

    int colbase = (st << 8) + (chunk << 3);
    bool cvalid = colbase < NN;
    const __half* base = xh + ((size_t)(b * FF) + (w << 5) + par) * NN + colbase;

    float up0 = 0, up1 = 0, up2 = 0, up3 = 0, up4 = 0, up5 = 0, up6 = 0, up7 = 0;
#pragma unroll
    for (int g = 0; g < 4; ++g) {
        f32x4 hv[4];
#pragma unroll
        for (int r = 0; r < 4; ++r) {
            if (cvalid) hv[r] = *(const f32x4*)(base + (size_t)((g << 3) + (r << 1)) * NN);
            else        hv[r] = (f32x4){0.f, 0.f, 0.f, 0.f};
        }
#pragma unroll
        for (int r = 0; r < 4; ++r) {
            int row = (w << 5) + par + (g << 3) + (r << 1);
            *(f32x4*)&tile[row][(chunk ^ (row & 7)) << 3] = hv[r];
            H8 u; u.v = hv[r];
            float c = s_cK[row];
            float2 q0 = __half22float2(u.h[0]);
            float2 q1 = __half22float2(u.h[1]);
            float2 q2 = __half22float2(u.h[2]);
            float2 q3 = __half22float2(u.h[3]);
            up0 = fmaf(c, q0.x, up0); up1 = fmaf(c, q0.y, up1);
            up2 = fmaf(c, q1.x, up2); up3 = fmaf(c, q1.y, up3);
            up4 = fmaf(c, q2.x, up4); up5 = fmaf(c, q2.y, up5);
            up6 = fmaf(c, q3.x, up6); up7 = fmaf(c, q3.y, up7);
        }
    }
    up0 += __shfl_xor(up0, 32); up1 += __shfl_xor(up1, 32);
    up2 += __shfl_xor(up2, 32); up3 += __shfl_xor(up3, 32);
    up4 += __shfl_xor(up4, 32); up5 += __shfl_xor(up5, 32);
    up6 += __shfl_xor(up6, 32); up7 += __shfl_xor(up7, 32);
    if (!par) {
        f32x4 v0 = {up0, up1, up2, up3}, v1 = {up4, up5, up6, up7};
        *(f32x4*)&s_u[w][chunk << 3]       = v0;
        *(f32x4*)&s_u[w][(chunk << 3) + 4] = v1;
    }
    __syncthreads();

    const float scale = 0.0625f;
    float uu = -INFINITY;
    if (tid < SC) {
        int col = (st << 8) + tid;
        if (col < NN) {
            float usum = 0.f;
#pragma unroll
            for (int ww = 0; ww < 8; ++ww) usum += s_u[ww][tid];
            uu = (usum + cK0[b]) * scale;
        }
    }
    float m = uu;
#pragma unroll
    for (int off = 32; off; off >>= 1) m = fmaxf(m, __shfl_xor(m, off));
    if (!lane && w < 4) s_red[w] = m;
    __syncthreads();
    float M = fmaxf(fmaxf(s_red[0], s_red[1]), fmaxf(s_red[2], s_red[3]));
    float e = (uu > -INFINITY) ? __expf(uu - M) : 0.f;
    if (tid < SC) s_p[tid] = e;
    float ssum = e;
#pragma unroll
    for (int off = 32; off; off >>= 1) ssum += __shfl_xor(ssum, off);
    if (!lane && w < 4) s_red2[w] = ssum;
    __syncthreads();
    if (!tid) {
        m_part[(b << 3) + st] = M;
        s_part[(b << 3) + st] = s_red2[0] + s_red2[1] + s_red2[2] + s_red2[3];
    }

    f32x4 pv0 = *(const f32x4*)&s_p[chunk << 3];
    f32x4 pv1 = *(const f32x4*)&s_p[(chunk << 3) + 4];
    float acc[16];
#pragma unroll
    for (int k = 0; k < 16; ++k) {
        int row = (w << 5) + par + (k << 1);
        H8 u; u.v = *(const f32x4*)&tile[row][(chunk ^ (row & 7)) << 3];
        float2 q0 = __half22float2(u.h[0]);
        float2 q1 = __half22float2(u.h[1]);
        float2 q2 = __half22float2(u.h[2]);
        float2 q3 = __half22float2(u.h[3]);
        float a = 0.f;
        a = fmaf(pv0.x, q0.x, a); a = fmaf(pv0.y, q0.y, a);
        a = fmaf(pv0.z, q1.x, a); a = fmaf(pv0.w, q1.y, a);
        a = fmaf(pv1.x, q2.x, a); a = fmaf(pv1.y, q2.y, a);
        a = fmaf(pv1.z, q3.x, a); a = fmaf(pv1.w, q3.y, a);
        acc[k] = a;
    }
    __syncthreads();
    float* tbuf = (float*)&tile[0][0];
#pragma unroll
    for (int k = 0; k < 16; ++k)
        tbuf[(w << 10) + ((par + (k << 1)) << 5) + chunk] = acc[k];
    __syncthreads();
    {
        int row = tid >> 1, half = tid & 1;
        const float* srcp = tbuf + ((row >> 5) << 10) + ((row & 31) << 5) + (half << 4);
        f32x4 a0 = *(const f32x4*)srcp;
        f32x4 a1 = *(const f32x4*)(srcp + 4);
        f32x4 a2 = *(const f32x4*)(srcp + 8);
        f32x4 a3 = *(const f32x4*)(srcp + 12);
        float sm = ((a0.x + a0.y) + (a0.z + a0.w)) + ((a1.x + a1.y) + (a1.z + a1.w)) +
                   ((a2.x + a2.y) + (a2.z + a2.w)) + ((a3.x + a3.y) + (a3.z + a3.w));
        sm += __shfl_xor(sm, 1);
        if (!half) y_part[(size_t)((b << 3) + st) * FF + row] = sm;
    }
}

// -------- K4: combine -> dense chain, wave-per-row coalesced --------
__global__ __launch_bounds__(256) void k_dense(
    const float* __restrict__ y_part, const float* __restrict__ m_part,
    const float* __restrict__ s_part,
    const float* __restrict__ Wnode, const float* __restrict__ bnode,
    const float* __restrict__ Wproj, const float* __restrict__ bproj,
    float* __restrict__ cL, float* __restrict__ cL0)
{
    int b = blockIdx.x, tid = threadIdx.x, w = tid >> 6, lane = tid & 63;
    __shared__ float s_y[FF], s_v[FF], s_n[FF], s_b1[FF], s_b2[FF], s_red[FF];

    s_b1[tid] = bnode[FF + tid];
    s_b2[tid] = bproj[tid];
    float M = -INFINITY;
#pragma unroll
    for (int s = 0; s < 8; ++s) M = fmaxf(M, m_part[(b << 3) + s]);
    float S = 0.f, wgt[8];
#pragma unroll
    for (int s = 0; s < 8; ++s) {
        wgt[s] = __expf(m_part[(b << 3) + s] - M);
        S = fmaf(wgt[s], s_part[(b << 3) + s], S);
    }
    float invS = 1.0f / S;
    float acc = 0.f;
#pragma unroll
    for (int s = 0; s < 8; ++s)
        acc = fmaf(wgt[s], y_part[(size_t)((b << 3) + s) * FF + tid], acc);
    s_y[tid] = acc * invS;
    __syncthreads();

    // nc_pre: wave-per-row over Wnode_V
    {
        f32x4 yv = *(const f32x4*)&s_y[lane << 2];
        for (int k = 0; k < 64; k += 4) {
            int fb = (w << 6) + k;
            f32x4 w0 = *(const f32x4*)(Wnode + (size_t)(FF + fb) * FF + (lane << 2));
            f32x4 w1 = *(const f32x4*)(Wnode + (size_t)(FF + fb + 1) * FF + (lane << 2));
            f32x4 w2 = *(const f32x4*)(Wnode + (size_t)(FF + fb + 2) * FF + (lane << 2));
            f32x4 w3 = *(const f32x4*)(Wnode + (size_t)(FF + fb + 3) * FF + (lane << 2));
            float p0 = dot4(w0, yv), p1 = dot4(w1, yv), p2 = dot4(w2, yv), p3 = dot4(w3, yv);
#pragma unroll
            for (int off = 32; off; off >>= 1) {
                p0 += __shfl_xor(p0, off);
                p1 += __shfl_xor(p1, off);
                p2 += __shfl_xor(p2, off);
                p3 += __shfl_xor(p3, off);
            }
            if (lane == 0) {
                s_v[fb]     = p0 + s_b1[fb];
                s_v[fb + 1] = p1 + s_b1[fb + 1];
                s_v[fb + 2] = p2 + s_b1[fb + 2];
                s_v[fb + 3] = p3 + s_b1[fb + 3];
            }
        }
    }
    __syncthreads();
    // nc2: wave-per-row over Wproj
    {
        f32x4 vv = *(const f32x4*)&s_v[lane << 2];
        for (int k = 0; k < 64; k += 4) {
            int fb = (w << 6) + k;
            f32x4 w0 = *(const f32x4*)(Wproj + (size_t)fb * FF + (lane << 2));
            f32x4 w1 = *(const f32x4*)(Wproj + (size_t)(fb + 1) * FF + (lane << 2));
            f32x4 w2 = *(const f32x4*)(Wproj + (size_t)(fb + 2) * FF + (lane << 2));
            f32x4 w3 = *(const f32x4*)(Wproj + (size_t)(fb + 3) * FF + (lane << 2));
            float p0 = dot4(w0, vv), p1 = dot4(w1, vv), p2 = dot4(w2, vv), p3 = dot4(w3, vv);
#pragma unroll
            for (int off = 32; off; off >>= 1) {
                p0 += __shfl_xor(p0, off);
                p1 += __shfl_xor(p1, off);
                p2 += __shfl_xor(p2, off);
                p3 += __shfl_xor(p3, off);
            }
            if (lane == 0) {
                s_n[fb]     = p0 + s_b2[fb];
                s_n[fb + 1] = p1 + s_b2[fb + 1];
                s_n[fb + 2] = p2 + s_b2[fb + 2];
                s_n[fb + 3] = p3 + s_b2[fb + 3];
            }
        }
    }
    __syncthreads();
    // cL: column-coalesced 8-deep
    {
        float a0 = 0, a1 = 0, a2 = 0, a3 = 0, a4 = 0, a5 = 0, a6 = 0, a7 = 0;
        for (int g = 0; g < FF; g += 8) {
            float w0 = Wnode[(size_t)(2 * FF + g + 0) * FF + tid];
            float w1 = Wnode[(size_t)(2 * FF + g + 1) * FF + tid];
            float w2 = Wnode[(size_t)(2 * FF + g + 2) * FF + tid];
            float w3 = Wnode[(size_t)(2 * FF + g + 3) * FF + tid];
            float w4 = Wnode[(size_t)(2 * FF + g + 4) * FF + tid];
            float w5 = Wnode[(size_t)(2 * FF + g + 5) * FF + tid];
            float w6 = Wnode[(size_t)(2 * FF + g + 6) * FF + tid];
            float w7 = Wnode[(size_t)(2 * FF + g + 7) * FF + tid];
            a0 = fmaf(s_n[g + 0], w0, a0); a1 = fmaf(s_n[g + 1], w1, a1);
            a2 = fmaf(s_n[g + 2], w2, a2); a3 = fmaf(s_n[g + 3], w3, a3);
            a4 = fmaf(s_n[g + 4], w4, a4); a5 = fmaf(s_n[g + 5], w5, a5);
            a6 = fmaf(s_n[g + 6], w6, a6); a7 = fmaf(s_n[g + 7], w7, a7);
        }
        cL[b * FF + tid] = ((a0 + a1) + (a2 + a3)) + ((a4 + a5) + (a6 + a7));
    }
    s_red[tid] = s_n[tid] * bnode[2 * FF + tid];
    __syncthreads();
    for (int s = 128; s > 0; s >>= 1) {
        if (tid < s) s_red[tid] += s_red[tid + s];
        __syncthreads();
    }
    if (tid == 0) cL0[b] = s_red[0];
}

// -------- K5: logits + tanh (r10 best) --------
__global__ __launch_bounds__(512) void k_logits(const __half* __restrict__ xh,
                                                const float* __restrict__ cL,
                                                const float* __restrict__ cL0,
                                                float* __restrict__ out)
{
    int b = blockIdx.x >> 3, st = blockIdx.x & 7;
    int tid = threadIdx.x, w = tid >> 6, lane = tid & 63;
    int par = lane >> 5, chunk = lane & 31;
    __shared__ float s_cL[FF];
    __shared__ float s_acc[8][SC];
    if (tid < FF) s_cL[tid] = cL[b * FF + tid];
    __syncthreads();

    int colbase = (st << 8) + (chunk << 3);
    bool cvalid = colbase < NN;
    const __half* base = xh + ((size_t)(b * FF) + (w << 5) + par) * NN + colbase;
    float up0 = 0, up1 = 0, up2 = 0, up3 = 0, up4 = 0, up5 = 0, up6 = 0, up7 = 0;
    if (cvalid) {
#pragma unroll
        for (int g = 0; g < 4; ++g) {
            f32x4 hv[4];
#pragma unroll
            for (int r = 0; r < 4; ++r)
                hv[r] = *(const f32x4*)(base + (size_t)((g << 3) + (r << 1)) * NN);
#pragma unroll
            for (int r = 0; r < 4; ++r) {
                int row = (w << 5) + par + (g << 3) + (r << 1);
                H8 u; u.v = hv[r];
                float c = s_cL[row];
                float2 q0 = __half22float2(u.h[0]);
                float2 q1 = __half22float2(u.h[1]);
                float2 q2 = __half22float2(u.h[2]);
                float2 q3 = __half22float2(u.h[3]);
                up0 = fmaf(c, q0.x, up0); up1 = fmaf(c, q0.y, up1);
                up2 = fmaf(c, q1.x, up2); up3 = fmaf(c, q1.y, up3);
                up4 = fmaf(c, q2.x, up4); up5 = fmaf(c, q2.y, up5);
                up6 = fmaf(c, q3.x, up6); up7 = fmaf(c, q3.y, up7);
            }
        }
    }
    up0 += __shfl_xor(up0, 32); up1 += __shfl_xor(up1, 32);
    up2 += __shfl_xor(up2, 32); up3 += __shfl_xor(up3, 32);
    up4 += __shfl_xor(up4, 32); up5 += __shfl_xor(up5, 32);
    up6 += __shfl_xor(up6, 32); up7 += __shfl_xor(up7, 32);
    if (!par) {
        f32x4 v0 = {up0, up1, up2, up3}, v1 = {up4, up5, up6, up7};
        *(f32x4*)&s_acc[w][chunk << 3]       = v0;
        *(f32x4*)&s_acc[w][(chunk << 3) + 4] = v1;
    }
    __syncthreads();
    if (tid < SC) {
        int col = (st << 8) + tid;
        if (col < NN) {
            float t = 0.f;
#pragma unroll
            for (int ww = 0; ww < 8; ++ww) t += s_acc[ww][tid];
            out[(size_t)b * NN + col] = tanhf((t + cL0[b]) * 0.0625f) * 10.f;
        }
    }
}

extern "C" void kernel_launch(void* const* d_in, const int* in_sizes, int n_in,
                              void* d_out, int out_size, void* d_ws, size_t ws_size,
                              hipStream_t stream) {
    const float* x     = (const float*)d_in[0];
    const int*   lc    = (const int*)d_in[1];
    const float* Wg    = (const float*)d_in[2];
    const float* bg    = (const float*)d_in[3];
    const float* Wnode = (const float*)d_in[4];
    const float* bnode = (const float*)d_in[5];
    const float* Wlc   = (const float*)d_in[6];
    const float* blc   = (const float*)d_in[7];
    const float* Wproj = (const float*)d_in[8];
    const float* bproj = (const float*)d_in[9];
    float* out = (float*)d_out;

    float* ws     = (float*)d_ws;
    float* glb    = ws + 0;          // B*F
    float* xg     = ws + 32768;      // B*F*2
    float* cK     = ws + 98304;      // B*F
    float* cK0    = ws + 131072;     // B
    float* m_part = ws + 132096;     // B*8
    float* s_part = ws + 134144;     // B*8
    float* cL     = ws + 136192;     // B*F
    float* cL0    = ws + 168960;     // B
    float* y_part = ws + 169984;     // B*8*F
    __half* xh    = (__half*)(ws + (2 << 20));  // 131 MB at 8 MB offset

    k_convmax<<<BB * FF / 4, 256, 0, stream>>>(x, lc, xh, glb, xg);
    k_prep   <<<BB, 256, 0, stream>>>(xg, glb, Wg, bg, Wnode, bnode, Wlc, blc, cK, cK0);
    k_attn   <<<BB * SW, 512, 0, stream>>>(xh, cK, cK0, y_part, m_part, s_part);
    k_dense  <<<BB, 256, 0, stream>>>(y_part, m_part, s_part, Wnode, bnode, Wproj, bproj, cL, cL0);
    k_logits <<<BB * SW, 512, 0, stream>>>(xh, cL, cL0, out);
}

// Round 16
// 177.490 us; speedup vs baseline: 21.8949x; 1.0299x over previous
//
#include <hip/hip_runtime.h>
#include <hip/hip_fp16.h>
#include <math.h>

#define BB 128
#define FF 256
#define NN 2000
#define SWA 16    // attn stripes per batch
#define SCA 128   // attn cols per stripe
#define SWL 8     // logits stripes per batch
#define SCL 256   // logits cols per stripe

typedef float f32x4 __attribute__((ext_vector_type(4)));
union H8 { f32x4 v; __half2 h[4]; };

__device__ __forceinline__ float sel8(f32x4 a, f32x4 b, int e) {
    float v;
    switch (e) {
        case 0: v = a.x; break; case 1: v = a.y; break;
        case 2: v = a.z; break; case 3: v = a.w; break;
        case 4: v = b.x; break; case 5: v = b.y; break;
        case 6: v = b.z; break; default: v = b.w; break;
    }
    return v;
}

__device__ __forceinline__ float dot4(f32x4 a, f32x4 b) {
    float s = a.x * b.x;
    s = fmaf(a.y, b.y, s);
    s = fmaf(a.z, b.z, s);
    s = fmaf(a.w, b.w, s);
    return s;
}

// -------- K1: x -> fp16, row max, last/current column extraction --------
__global__ __launch_bounds__(256) void k_convmax(const float* __restrict__ x,
                                                 const int* __restrict__ lc,
                                                 __half* __restrict__ xh,
                                                 float* __restrict__ glb,
                                                 float* __restrict__ xg) {
    int row  = (blockIdx.x << 2) | (threadIdx.x >> 6);
    int lane = threadIdx.x & 63;
    int b    = row >> 8;
    const int c0 = lc[2 * b], c1 = lc[2 * b + 1];
    const int i0 = c0 >> 3, e0 = c0 & 7;
    const int i1 = c1 >> 3, e1 = c1 & 7;
    const f32x4* src = (const f32x4*)(x + (size_t)row * NN);
    f32x4*       dst = (f32x4*)(xh + (size_t)row * NN);
    float m = -INFINITY;
    for (int i = lane; i < 250; i += 64) {
        f32x4 a = __builtin_nontemporal_load(src + 2 * i);
        f32x4 q = __builtin_nontemporal_load(src + 2 * i + 1);
        m = fmaxf(m, fmaxf(fmaxf(a.x, a.y), fmaxf(a.z, a.w)));
        m = fmaxf(m, fmaxf(fmaxf(q.x, q.y), fmaxf(q.z, q.w)));
        if (i == i0) xg[row * 2]     = sel8(a, q, e0);
        if (i == i1) xg[row * 2 + 1] = sel8(a, q, e1);
        H8 o;
        o.h[0] = __floats2half2_rn(a.x, a.y);
        o.h[1] = __floats2half2_rn(a.z, a.w);
        o.h[2] = __floats2half2_rn(q.x, q.y);
        o.h[3] = __floats2half2_rn(q.z, q.w);
        dst[i] = o.v;
    }
#pragma unroll
    for (int off = 32; off; off >>= 1) m = fmaxf(m, __shfl_xor(m, off));
    if (!lane) glb[row] = m;
}

// -------- K2: prep, wave-per-row coalesced matvecs (r15 best) --------
__global__ __launch_bounds__(256) void k_prep(
    const float* __restrict__ xg, const float* __restrict__ glb,
    const float* __restrict__ Wg, const float* __restrict__ bg,
    const float* __restrict__ Wnode, const float* __restrict__ bnode,
    const float* __restrict__ Wlc, const float* __restrict__ blc,
    float* __restrict__ cK, float* __restrict__ cK0)
{
    int b = blockIdx.x, tid = threadIdx.x, w = tid >> 6, lane = tid & 63;
    __shared__ float s_glb[FF], s_ctx[2 * FF], s_cQ[FF], s_bias[FF], s_red[FF];
    s_glb[tid] = glb[b * FF + tid];
    float2 g2 = ((const float2*)xg)[b * FF + tid];
    s_ctx[tid]      = g2.x;
    s_ctx[FF + tid] = g2.y;
    s_bias[tid] = bg[tid] + blc[tid];
    __syncthreads();

    f32x4 gv  = *(const f32x4*)&s_glb[lane << 2];
    f32x4 c0v = *(const f32x4*)&s_ctx[lane << 3];
    f32x4 c1v = *(const f32x4*)&s_ctx[(lane << 3) + 4];

    for (int k = 0; k < 64; k += 4) {
        float p0, p1, p2, p3;
        {
            int fb = (w << 6) + k;
            f32x4 wg0 = *(const f32x4*)(Wg + (size_t)fb * FF + (lane << 2));
            f32x4 wg1 = *(const f32x4*)(Wg + (size_t)(fb + 1) * FF + (lane << 2));
            f32x4 wg2 = *(const f32x4*)(Wg + (size_t)(fb + 2) * FF + (lane << 2));
            f32x4 wg3 = *(const f32x4*)(Wg + (size_t)(fb + 3) * FF + (lane << 2));
            f32x4 wa0 = *(const f32x4*)(Wlc + (size_t)fb * 2 * FF + (lane << 3));
            f32x4 wb0 = *(const f32x4*)(Wlc + (size_t)fb * 2 * FF + (lane << 3) + 4);
            f32x4 wa1 = *(const f32x4*)(Wlc + (size_t)(fb + 1) * 2 * FF + (lane << 3));
            f32x4 wb1 = *(const f32x4*)(Wlc + (size_t)(fb + 1) * 2 * FF + (lane << 3) + 4);
            f32x4 wa2 = *(const f32x4*)(Wlc + (size_t)(fb + 2) * 2 * FF + (lane << 3));
            f32x4 wb2 = *(const f32x4*)(Wlc + (size_t)(fb + 2) * 2 * FF + (lane << 3) + 4);
            f32x4 wa3 = *(const f32x4*)(Wlc + (size_t)(fb + 3) * 2 * FF + (lane << 3));
            f32x4 wb3 = *(const f32x4*)(Wlc + (size_t)(fb + 3) * 2 * FF + (lane << 3) + 4);
            p0 = dot4(wg0, gv) + dot4(wa0, c0v) + dot4(wb0, c1v);
            p1 = dot4(wg1, gv) + dot4(wa1, c0v) + dot4(wb1, c1v);
            p2 = dot4(wg2, gv) + dot4(wa2, c0v) + dot4(wb2, c1v);
            p3 = dot4(wg3, gv) + dot4(wa3, c0v) + dot4(wb3, c1v);
        }
#pragma unroll
        for (int off = 32; off; off >>= 1) {
            p0 += __shfl_xor(p0, off);
            p1 += __shfl_xor(p1, off);
            p2 += __shfl_xor(p2, off);
            p3 += __shfl_xor(p3, off);
        }
        if (lane == 0) {
            int fb = (w << 6) + k;
            s_cQ[fb]     = p0 + s_bias[fb];
            s_cQ[fb + 1] = p1 + s_bias[fb + 1];
            s_cQ[fb + 2] = p2 + s_bias[fb + 2];
            s_cQ[fb + 3] = p3 + s_bias[fb + 3];
        }
    }
    __syncthreads();

    {
        float a0 = 0, a1 = 0, a2 = 0, a3 = 0, a4 = 0, a5 = 0, a6 = 0, a7 = 0;
        for (int g = 0; g < FF; g += 8) {
            float w0 = Wnode[(size_t)(g + 0) * FF + tid];
            float w1 = Wnode[(size_t)(g + 1) * FF + tid];
            float w2 = Wnode[(size_t)(g + 2) * FF + tid];
            float w3 = Wnode[(size_t)(g + 3) * FF + tid];
            float w4 = Wnode[(size_t)(g + 4) * FF + tid];
            float w5 = Wnode[(size_t)(g + 5) * FF + tid];
            float w6 = Wnode[(size_t)(g + 6) * FF + tid];
            float w7 = Wnode[(size_t)(g + 7) * FF + tid];
            a0 = fmaf(s_cQ[g + 0], w0, a0); a1 = fmaf(s_cQ[g + 1], w1, a1);
            a2 = fmaf(s_cQ[g + 2], w2, a2); a3 = fmaf(s_cQ[g + 3], w3, a3);
            a4 = fmaf(s_cQ[g + 4], w4, a4); a5 = fmaf(s_cQ[g + 5], w5, a5);
            a6 = fmaf(s_cQ[g + 6], w6, a6); a7 = fmaf(s_cQ[g + 7], w7, a7);
        }
        cK[b * FF + tid] = ((a0 + a1) + (a2 + a3)) + ((a4 + a5) + (a6 + a7));
    }
    s_red[tid] = s_cQ[tid] * bnode[tid];
    __syncthreads();
    for (int s = 128; s > 0; s >>= 1) {
        if (tid < s) s_red[tid] += s_red[tid + s];
        __syncthreads();
    }
    if (tid == 0) cK0[b] = s_red[0];
}

// -------- K3: fused attn, REGISTER tile (8 rows x 8 cols / thread), 16 stripes --------
// 2048 blocks x 512 thr. Wave w rows [w*32,w*32+32). par=lane>>4 (4 rows),
// chunk=lane&15 (16 x 8-col chunks). hv[8] holds thread's sub-tile across softmax.
__global__ __launch_bounds__(512) void k_attn(
    const __half* __restrict__ xh,
    const float* __restrict__ cK, const float* __restrict__ cK0,
    float* __restrict__ y_part, float* __restrict__ m_part,
    float* __restrict__ s_part)
{
    int b = blockIdx.x >> 4, st = blockIdx.x & 15;
    int tid = threadIdx.x, w = tid >> 6, lane = tid & 63;
    int par = lane >> 4, chunk = lane & 15;
    __shared__ float tbuf[8][512];           // 16 KB wave-private transpose scratch
    __shared__ float s_u[8][SCA];            // 4 KB
    __shared__ float s_p[SCA];
    __shared__ float s_cK[FF];
    __shared__ float s_red[8], s_red2[8];
    if (tid < FF) s_cK[tid] = cK[b * FF + tid];
    __syncthreads();

    int colbase = (st << 7) + (chunk << 3);
    bool cvalid = colbase < NN;              // 8-col chunk fully valid or fully invalid
    const __half* base = xh + ((size_t)(b * FF) + (w << 5) + par) * NN + colbase;
    const f32x4 zero = {0.f, 0.f, 0.f, 0.f};

    // ---- pass 1: 8 loads deep into registers; u-partials ----
    f32x4 hv[8];
#pragma unroll
    for (int r = 0; r < 8; ++r)
        hv[r] = cvalid ? *(const f32x4*)(base + (size_t)(r << 2) * NN) : zero;

    float uc0 = 0, uc1 = 0, uc2 = 0, uc3 = 0, uc4 = 0, uc5 = 0, uc6 = 0, uc7 = 0;
#pragma unroll
    for (int r = 0; r < 8; ++r) {
        int row = (w << 5) + (r << 2) + par;
        H8 u; u.v = hv[r];
        float c = s_cK[row];
        float2 q0 = __half22float2(u.h[0]);
        float2 q1 = __half22float2(u.h[1]);
        float2 q2 = __half22float2(u.h[2]);
        float2 q3 = __half22float2(u.h[3]);
        uc0 = fmaf(c, q0.x, uc0); uc1 = fmaf(c, q0.y, uc1);
        uc2 = fmaf(c, q1.x, uc2); uc3 = fmaf(c, q1.y, uc3);
        uc4 = fmaf(c, q2.x, uc4); uc5 = fmaf(c, q2.y, uc5);
        uc6 = fmaf(c, q3.x, uc6); uc7 = fmaf(c, q3.y, uc7);
    }
    // reduce across par (lane bits 4,5)
    uc0 += __shfl_xor(uc0, 16); uc0 += __shfl_xor(uc0, 32);
    uc1 += __shfl_xor(uc1, 16); uc1 += __shfl_xor(uc1, 32);
    uc2 += __shfl_xor(uc2, 16); uc2 += __shfl_xor(uc2, 32);
    uc3 += __shfl_xor(uc3, 16); uc3 += __shfl_xor(uc3, 32);
    uc4 += __shfl_xor(uc4, 16); uc4 += __shfl_xor(uc4, 32);
    uc5 += __shfl_xor(uc5, 16); uc5 += __shfl_xor(uc5, 32);
    uc6 += __shfl_xor(uc6, 16); uc6 += __shfl_xor(uc6, 32);
    uc7 += __shfl_xor(uc7, 16); uc7 += __shfl_xor(uc7, 32);
    if (par == 0) {
        f32x4 v0 = {uc0, uc1, uc2, uc3}, v1 = {uc4, uc5, uc6, uc7};
        *(f32x4*)&s_u[w][chunk << 3]       = v0;
        *(f32x4*)&s_u[w][(chunk << 3) + 4] = v1;
    }
    __syncthreads();

    // ---- stripe softmax over 128 cols (threads 0..127) ----
    const float scale = 0.0625f;
    float uu = -INFINITY;
    if (tid < SCA) {
        int col = (st << 7) + tid;
        if (col < NN) {
            float usum = 0.f;
#pragma unroll
            for (int ww = 0; ww < 8; ++ww) usum += s_u[ww][tid];
            uu = (usum + cK0[b]) * scale;
        }
    }
    float m = uu;
#pragma unroll
    for (int off = 32; off; off >>= 1) m = fmaxf(m, __shfl_xor(m, off));
    if (!lane && w < 2) s_red[w] = m;
    __syncthreads();
    float M = fmaxf(s_red[0], s_red[1]);
    float e = (uu > -INFINITY) ? __expf(uu - M) : 0.f;
    if (tid < SCA) s_p[tid] = e;
    float ssum = e;
#pragma unroll
    for (int off = 32; off; off >>= 1) ssum += __shfl_xor(ssum, off);
    if (!lane && w < 2) s_red2[w] = ssum;
    __syncthreads();
    if (!tid) {
        m_part[(b << 4) + st] = M;
        s_part[(b << 4) + st] = s_red2[0] + s_red2[1];
    }

    // ---- pass 2: y from REGISTERS; LDS transpose-reduce (wave-private) ----
    f32x4 pv0 = *(const f32x4*)&s_p[chunk << 3];
    f32x4 pv1 = *(const f32x4*)&s_p[(chunk << 3) + 4];
#pragma unroll
    for (int r = 0; r < 8; ++r) {
        H8 u; u.v = hv[r];
        float2 q0 = __half22float2(u.h[0]);
        float2 q1 = __half22float2(u.h[1]);
        float2 q2 = __half22float2(u.h[2]);
        float2 q3 = __half22float2(u.h[3]);
        float a = 0.f;
        a = fmaf(pv0.x, q0.x, a); a = fmaf(pv0.y, q0.y, a);
        a = fmaf(pv0.z, q1.x, a); a = fmaf(pv0.w, q1.y, a);
        a = fmaf(pv1.x, q2.x, a); a = fmaf(pv1.y, q2.y, a);
        a = fmaf(pv1.z, q3.x, a); a = fmaf(pv1.w, q3.y, a);
        tbuf[w][(((r << 2) + par) << 4) + chunk] = a;   // wave-private: no barrier
    }
    {
        int row = tid >> 1, half = tid & 1;              // row 0..255; wave w reads tbuf[w]
        const float* srcp = &tbuf[row >> 5][((row & 31) << 4) + (half << 3)];
        f32x4 a0 = *(const f32x4*)srcp;
        f32x4 a1 = *(const f32x4*)(srcp + 4);
        float sm = ((a0.x + a0.y) + (a0.z + a0.w)) + ((a1.x + a1.y) + (a1.z + a1.w));
        sm += __shfl_xor(sm, 1);
        if (!half) y_part[(size_t)((b << 4) + st) * FF + row] = sm;
    }
}

// -------- K4: combine 16 stripe partials -> y -> dense chain (r15 best) --------
__global__ __launch_bounds__(256) void k_dense(
    const float* __restrict__ y_part, const float* __restrict__ m_part,
    const float* __restrict__ s_part,
    const float* __restrict__ Wnode, const float* __restrict__ bnode,
    const float* __restrict__ Wproj, const float* __restrict__ bproj,
    float* __restrict__ cL, float* __restrict__ cL0)
{
    int b = blockIdx.x, tid = threadIdx.x, w = tid >> 6, lane = tid & 63;
    __shared__ float s_y[FF], s_v[FF], s_n[FF], s_b1[FF], s_b2[FF], s_red[FF];

    s_b1[tid] = bnode[FF + tid];
    s_b2[tid] = bproj[tid];
    float M = -INFINITY;
#pragma unroll
    for (int s = 0; s < 16; ++s) M = fmaxf(M, m_part[(b << 4) + s]);
    float S = 0.f, wgt[16];
#pragma unroll
    for (int s = 0; s < 16; ++s) {
        wgt[s] = __expf(m_part[(b << 4) + s] - M);
        S = fmaf(wgt[s], s_part[(b << 4) + s], S);
    }
    float invS = 1.0f / S;
    float acc = 0.f;
#pragma unroll
    for (int s = 0; s < 16; ++s)
        acc = fmaf(wgt[s], y_part[(size_t)((b << 4) + s) * FF + tid], acc);
    s_y[tid] = acc * invS;
    __syncthreads();

    {
        f32x4 yv = *(const f32x4*)&s_y[lane << 2];
        for (int k = 0; k < 64; k += 4) {
            int fb = (w << 6) + k;
            f32x4 w0 = *(const f32x4*)(Wnode + (size_t)(FF + fb) * FF + (lane << 2));
            f32x4 w1 = *(const f32x4*)(Wnode + (size_t)(FF + fb + 1) * FF + (lane << 2));
            f32x4 w2 = *(const f32x4*)(Wnode + (size_t)(FF + fb + 2) * FF + (lane << 2));
            f32x4 w3 = *(const f32x4*)(Wnode + (size_t)(FF + fb + 3) * FF + (lane << 2));
            float p0 = dot4(w0, yv), p1 = dot4(w1, yv), p2 = dot4(w2, yv), p3 = dot4(w3, yv);
#pragma unroll
            for (int off = 32; off; off >>= 1) {
                p0 += __shfl_xor(p0, off);
                p1 += __shfl_xor(p1, off);
                p2 += __shfl_xor(p2, off);
                p3 += __shfl_xor(p3, off);
            }
            if (lane == 0) {
                s_v[fb]     = p0 + s_b1[fb];
                s_v[fb + 1] = p1 + s_b1[fb + 1];
                s_v[fb + 2] = p2 + s_b1[fb + 2];
                s_v[fb + 3] = p3 + s_b1[fb + 3];
            }
        }
    }
    __syncthreads();
    {
        f32x4 vv = *(const f32x4*)&s_v[lane << 2];
        for (int k = 0; k < 64; k += 4) {
            int fb = (w << 6) + k;
            f32x4 w0 = *(const f32x4*)(Wproj + (size_t)fb * FF + (lane << 2));
            f32x4 w1 = *(const f32x4*)(Wproj + (size_t)(fb + 1) * FF + (lane << 2));
            f32x4 w2 = *(const f32x4*)(Wproj + (size_t)(fb + 2) * FF + (lane << 2));
            f32x4 w3 = *(const f32x4*)(Wproj + (size_t)(fb + 3) * FF + (lane << 2));
            float p0 = dot4(w0, vv), p1 = dot4(w1, vv), p2 = dot4(w2, vv), p3 = dot4(w3, vv);
#pragma unroll
            for (int off = 32; off; off >>= 1) {
                p0 += __shfl_xor(p0, off);
                p1 += __shfl_xor(p1, off);
                p2 += __shfl_xor(p2, off);
                p3 += __shfl_xor(p3, off);
            }
            if (lane == 0) {
                s_n[fb]     = p0 + s_b2[fb];
                s_n[fb + 1] = p1 + s_b2[fb + 1];
                s_n[fb + 2] = p2 + s_b2[fb + 2];
                s_n[fb + 3] = p3 + s_b2[fb + 3];
            }
        }
    }
    __syncthreads();
    {
        float a0 = 0, a1 = 0, a2 = 0, a3 = 0, a4 = 0, a5 = 0, a6 = 0, a7 = 0;
        for (int g = 0; g < FF; g += 8) {
            float w0 = Wnode[(size_t)(2 * FF + g + 0) * FF + tid];
            float w1 = Wnode[(size_t)(2 * FF + g + 1) * FF + tid];
            float w2 = Wnode[(size_t)(2 * FF + g + 2) * FF + tid];
            float w3 = Wnode[(size_t)(2 * FF + g + 3) * FF + tid];
            float w4 = Wnode[(size_t)(2 * FF + g + 4) * FF + tid];
            float w5 = Wnode[(size_t)(2 * FF + g + 5) * FF + tid];
            float w6 = Wnode[(size_t)(2 * FF + g + 6) * FF + tid];
            float w7 = Wnode[(size_t)(2 * FF + g + 7) * FF + tid];
            a0 = fmaf(s_n[g + 0], w0, a0); a1 = fmaf(s_n[g + 1], w1, a1);
            a2 = fmaf(s_n[g + 2], w2, a2); a3 = fmaf(s_n[g + 3], w3, a3);
            a4 = fmaf(s_n[g + 4], w4, a4); a5 = fmaf(s_n[g + 5], w5, a5);
            a6 = fmaf(s_n[g + 6], w6, a6); a7 = fmaf(s_n[g + 7], w7, a7);
        }
        cL[b * FF + tid] = ((a0 + a1) + (a2 + a3)) + ((a4 + a5) + (a6 + a7));
    }
    s_red[tid] = s_n[tid] * bnode[2 * FF + tid];
    __syncthreads();
    for (int s = 128; s > 0; s >>= 1) {
        if (tid < s) s_red[tid] += s_red[tid + s];
        __syncthreads();
    }
    if (tid == 0) cL0[b] = s_red[0];
}

// -------- K5: logits + tanh, 8-deep loads --------
__global__ __launch_bounds__(512) void k_logits(const __half* __restrict__ xh,
                                                const float* __restrict__ cL,
                                                const float* __restrict__ cL0,
                                                float* __restrict__ out)
{
    int b = blockIdx.x >> 3, st = blockIdx.x & 7;
    int tid = threadIdx.x, w = tid >> 6, lane = tid & 63;
    int par = lane >> 5, chunk = lane & 31;
    __shared__ float s_cL[FF];
    __shared__ float s_acc[8][SCL];
    if (tid < FF) s_cL[tid] = cL[b * FF + tid];
    __syncthreads();

    int colbase = (st << 8) + (chunk << 3);
    bool cvalid = colbase < NN;
    const __half* base = xh + ((size_t)(b * FF) + (w << 5) + par) * NN + colbase;
    const f32x4 zero = {0.f, 0.f, 0.f, 0.f};
    float up0 = 0, up1 = 0, up2 = 0, up3 = 0, up4 = 0, up5 = 0, up6 = 0, up7 = 0;
#pragma unroll
    for (int h = 0; h < 2; ++h) {
        f32x4 hv[8];
#pragma unroll
        for (int r = 0; r < 8; ++r)
            hv[r] = cvalid ? *(const f32x4*)(base + (size_t)((h << 4) + (r << 1)) * NN) : zero;
#pragma unroll
        for (int r = 0; r < 8; ++r) {
            int row = (w << 5) + par + (h << 4) + (r << 1);
            H8 u; u.v = hv[r];
            float c = s_cL[row];
            float2 q0 = __half22float2(u.h[0]);
            float2 q1 = __half22float2(u.h[1]);
            float2 q2 = __half22float2(u.h[2]);
            float2 q3 = __half22float2(u.h[3]);
            up0 = fmaf(c, q0.x, up0); up1 = fmaf(c, q0.y, up1);
            up2 = fmaf(c, q1.x, up2); up3 = fmaf(c, q1.y, up3);
            up4 = fmaf(c, q2.x, up4); up5 = fmaf(c, q2.y, up5);
            up6 = fmaf(c, q3.x, up6); up7 = fmaf(c, q3.y, up7);
        }
    }
    up0 += __shfl_xor(up0, 32); up1 += __shfl_xor(up1, 32);
    up2 += __shfl_xor(up2, 32); up3 += __shfl_xor(up3, 32);
    up4 += __shfl_xor(up4, 32); up5 += __shfl_xor(up5, 32);
    up6 += __shfl_xor(up6, 32); up7 += __shfl_xor(up7, 32);
    if (!par) {
        f32x4 v0 = {up0, up1, up2, up3}, v1 = {up4, up5, up6, up7};
        *(f32x4*)&s_acc[w][chunk << 3]       = v0;
        *(f32x4*)&s_acc[w][(chunk << 3) + 4] = v1;
    }
    __syncthreads();
    if (tid < SCL) {
        int col = (st << 8) + tid;
        if (col < NN) {
            float t = 0.f;
#pragma unroll
            for (int ww = 0; ww < 8; ++ww) t += s_acc[ww][tid];
            out[(size_t)b * NN + col] = tanhf((t + cL0[b]) * 0.0625f) * 10.f;
        }
    }
}

extern "C" void kernel_launch(void* const* d_in, const int* in_sizes, int n_in,
                              void* d_out, int out_size, void* d_ws, size_t ws_size,
                              hipStream_t stream) {
    const float* x     = (const float*)d_in[0];
    const int*   lc    = (const int*)d_in[1];
    const float* Wg    = (const float*)d_in[2];
    const float* bg    = (const float*)d_in[3];
    const float* Wnode = (const float*)d_in[4];
    const float* bnode = (const float*)d_in[5];
    const float* Wlc   = (const float*)d_in[6];
    const float* blc   = (const float*)d_in[7];
    const float* Wproj = (const float*)d_in[8];
    const float* bproj = (const float*)d_in[9];
    float* out = (float*)d_out;

    float* ws     = (float*)d_ws;
    float* glb    = ws + 0;          // B*F
    float* xg     = ws + 32768;      // B*F*2
    float* cK     = ws + 98304;      // B*F
    float* cK0    = ws + 131072;     // B
    float* m_part = ws + 132096;     // B*16
    float* s_part = ws + 134144;     // B*16
    float* cL     = ws + 136192;     // B*F
    float* cL0    = ws + 168960;     // B
    float* y_part = ws + 169984;     // B*16*F = 524288
    __half* xh    = (__half*)(ws + (2 << 20));  // 131 MB at 8 MB offset

    k_convmax<<<BB * FF / 4, 256, 0, stream>>>(x, lc, xh, glb, xg);
    k_prep   <<<BB, 256, 0, stream>>>(xg, glb, Wg, bg, Wnode, bnode, Wlc, blc, cK, cK0);
    k_attn   <<<BB * SWA, 512, 0, stream>>>(xh, cK, cK0, y_part, m_part, s_part);
    k_dense  <<<BB, 256, 0, stream>>>(y_part, m_part, s_part, Wnode, bnode, Wproj, bproj, cL, cL0);
    k_logits <<<BB * SWL, 512, 0, stream>>>(xh, cL, cL0, out);
}

// Round 17
// 165.498 us; speedup vs baseline: 23.4815x; 1.0725x over previous
//
#include <hip/hip_runtime.h>
#include <hip/hip_fp16.h>
#include <math.h>

#define BB 128
#define FF 256
#define NN 2000
#define SWA 16    // stripes per batch (attn AND logits)
#define SCA 128   // cols per stripe
// xh tiled layout: xh_t[b][st][f][c], c in [0,128), cols padded to 2048 (pad zeroed)

typedef float f32x4 __attribute__((ext_vector_type(4)));
union H8 { f32x4 v; __half2 h[4]; };

__device__ __forceinline__ float sel8(f32x4 a, f32x4 b, int e) {
    float v;
    switch (e) {
        case 0: v = a.x; break; case 1: v = a.y; break;
        case 2: v = a.z; break; case 3: v = a.w; break;
        case 4: v = b.x; break; case 5: v = b.y; break;
        case 6: v = b.z; break; default: v = b.w; break;
    }
    return v;
}

__device__ __forceinline__ float dot4(f32x4 a, f32x4 b) {
    float s = a.x * b.x;
    s = fmaf(a.y, b.y, s);
    s = fmaf(a.z, b.z, s);
    s = fmaf(a.w, b.w, s);
    return s;
}

// -------- K1: x -> fp16 (stripe-tiled layout), row max, lc-gather --------
__global__ __launch_bounds__(256) void k_convmax(const float* __restrict__ x,
                                                 const int* __restrict__ lc,
                                                 __half* __restrict__ xh,
                                                 float* __restrict__ glb,
                                                 float* __restrict__ xg) {
    int row  = (blockIdx.x << 2) | (threadIdx.x >> 6);
    int lane = threadIdx.x & 63;
    int b    = row >> 8;
    int f    = row & 255;
    const int c0 = lc[2 * b], c1 = lc[2 * b + 1];
    const int i0 = c0 >> 3, e0 = c0 & 7;
    const int i1 = c1 >> 3, e1 = c1 & 7;
    const f32x4* src = (const f32x4*)(x + (size_t)row * NN);
    // tiled base for this row (in halves): ((b*16+st)*256 + f)*128 + c
    __half* trow = xh + ((size_t)(b << 4) * 256 + f) * 128;   // + st*32768 + c
    float m = -INFINITY;
    for (int i = lane; i < 250; i += 64) {
        f32x4 a = __builtin_nontemporal_load(src + 2 * i);
        f32x4 q = __builtin_nontemporal_load(src + 2 * i + 1);
        m = fmaxf(m, fmaxf(fmaxf(a.x, a.y), fmaxf(a.z, a.w)));
        m = fmaxf(m, fmaxf(fmaxf(q.x, q.y), fmaxf(q.z, q.w)));
        if (i == i0) xg[row * 2]     = sel8(a, q, e0);
        if (i == i1) xg[row * 2 + 1] = sel8(a, q, e1);
        H8 o;
        o.h[0] = __floats2half2_rn(a.x, a.y);
        o.h[1] = __floats2half2_rn(a.z, a.w);
        o.h[2] = __floats2half2_rn(q.x, q.y);
        o.h[3] = __floats2half2_rn(q.z, q.w);
        *(f32x4*)(trow + (size_t)(i >> 4) * 32768 + ((i & 15) << 3)) = o.v;
    }
    // zero the pad chunks (cols 2000..2047 = stripe 15, chunks 10..15)
    if (lane < 6) {
        int i = 250 + lane;
        f32x4 z = {0.f, 0.f, 0.f, 0.f};
        *(f32x4*)(trow + (size_t)15 * 32768 + ((i & 15) << 3)) = z;
    }
#pragma unroll
    for (int off = 32; off; off >>= 1) m = fmaxf(m, __shfl_xor(m, off));
    if (!lane) glb[row] = m;
}

// -------- K2: prep, wave-per-row coalesced matvecs (r15 best) --------
__global__ __launch_bounds__(256) void k_prep(
    const float* __restrict__ xg, const float* __restrict__ glb,
    const float* __restrict__ Wg, const float* __restrict__ bg,
    const float* __restrict__ Wnode, const float* __restrict__ bnode,
    const float* __restrict__ Wlc, const float* __restrict__ blc,
    float* __restrict__ cK, float* __restrict__ cK0)
{
    int b = blockIdx.x, tid = threadIdx.x, w = tid >> 6, lane = tid & 63;
    __shared__ float s_glb[FF], s_ctx[2 * FF], s_cQ[FF], s_bias[FF], s_red[FF];
    s_glb[tid] = glb[b * FF + tid];
    float2 g2 = ((const float2*)xg)[b * FF + tid];
    s_ctx[tid]      = g2.x;
    s_ctx[FF + tid] = g2.y;
    s_bias[tid] = bg[tid] + blc[tid];
    __syncthreads();

    f32x4 gv  = *(const f32x4*)&s_glb[lane << 2];
    f32x4 c0v = *(const f32x4*)&s_ctx[lane << 3];
    f32x4 c1v = *(const f32x4*)&s_ctx[(lane << 3) + 4];

    for (int k = 0; k < 64; k += 4) {
        float p0, p1, p2, p3;
        {
            int fb = (w << 6) + k;
            f32x4 wg0 = *(const f32x4*)(Wg + (size_t)fb * FF + (lane << 2));
            f32x4 wg1 = *(const f32x4*)(Wg + (size_t)(fb + 1) * FF + (lane << 2));
            f32x4 wg2 = *(const f32x4*)(Wg + (size_t)(fb + 2) * FF + (lane << 2));
            f32x4 wg3 = *(const f32x4*)(Wg + (size_t)(fb + 3) * FF + (lane << 2));
            f32x4 wa0 = *(const f32x4*)(Wlc + (size_t)fb * 2 * FF + (lane << 3));
            f32x4 wb0 = *(const f32x4*)(Wlc + (size_t)fb * 2 * FF + (lane << 3) + 4);
            f32x4 wa1 = *(const f32x4*)(Wlc + (size_t)(fb + 1) * 2 * FF + (lane << 3));
            f32x4 wb1 = *(const f32x4*)(Wlc + (size_t)(fb + 1) * 2 * FF + (lane << 3) + 4);
            f32x4 wa2 = *(const f32x4*)(Wlc + (size_t)(fb + 2) * 2 * FF + (lane << 3));
            f32x4 wb2 = *(const f32x4*)(Wlc + (size_t)(fb + 2) * 2 * FF + (lane << 3) + 4);
            f32x4 wa3 = *(const f32x4*)(Wlc + (size_t)(fb + 3) * 2 * FF + (lane << 3));
            f32x4 wb3 = *(const f32x4*)(Wlc + (size_t)(fb + 3) * 2 * FF + (lane << 3) + 4);
            p0 = dot4(wg0, gv) + dot4(wa0, c0v) + dot4(wb0, c1v);
            p1 = dot4(wg1, gv) + dot4(wa1, c0v) + dot4(wb1, c1v);
            p2 = dot4(wg2, gv) + dot4(wa2, c0v) + dot4(wb2, c1v);
            p3 = dot4(wg3, gv) + dot4(wa3, c0v) + dot4(wb3, c1v);
        }
#pragma unroll
        for (int off = 32; off; off >>= 1) {
            p0 += __shfl_xor(p0, off);
            p1 += __shfl_xor(p1, off);
            p2 += __shfl_xor(p2, off);
            p3 += __shfl_xor(p3, off);
        }
        if (lane == 0) {
            int fb = (w << 6) + k;
            s_cQ[fb]     = p0 + s_bias[fb];
            s_cQ[fb + 1] = p1 + s_bias[fb + 1];
            s_cQ[fb + 2] = p2 + s_bias[fb + 2];
            s_cQ[fb + 3] = p3 + s_bias[fb + 3];
        }
    }
    __syncthreads();

    {
        float a0 = 0, a1 = 0, a2 = 0, a3 = 0, a4 = 0, a5 = 0, a6 = 0, a7 = 0;
        for (int g = 0; g < FF; g += 8) {
            float w0 = Wnode[(size_t)(g + 0) * FF + tid];
            float w1 = Wnode[(size_t)(g + 1) * FF + tid];
            float w2 = Wnode[(size_t)(g + 2) * FF + tid];
            float w3 = Wnode[(size_t)(g + 3) * FF + tid];
            float w4 = Wnode[(size_t)(g + 4) * FF + tid];
            float w5 = Wnode[(size_t)(g + 5) * FF + tid];
            float w6 = Wnode[(size_t)(g + 6) * FF + tid];
            float w7 = Wnode[(size_t)(g + 7) * FF + tid];
            a0 = fmaf(s_cQ[g + 0], w0, a0); a1 = fmaf(s_cQ[g + 1], w1, a1);
            a2 = fmaf(s_cQ[g + 2], w2, a2); a3 = fmaf(s_cQ[g + 3], w3, a3);
            a4 = fmaf(s_cQ[g + 4], w4, a4); a5 = fmaf(s_cQ[g + 5], w5, a5);
            a6 = fmaf(s_cQ[g + 6], w6, a6); a7 = fmaf(s_cQ[g + 7], w7, a7);
        }
        cK[b * FF + tid] = ((a0 + a1) + (a2 + a3)) + ((a4 + a5) + (a6 + a7));
    }
    s_red[tid] = s_cQ[tid] * bnode[tid];
    __syncthreads();
    for (int s = 128; s > 0; s >>= 1) {
        if (tid < s) s_red[tid] += s_red[tid + s];
        __syncthreads();
    }
    if (tid == 0) cK0[b] = s_red[0];
}

// -------- K3: fused attn, register tile over TILED xh (sequential streams) --------
__global__ __launch_bounds__(512) void k_attn(
    const __half* __restrict__ xh,
    const float* __restrict__ cK, const float* __restrict__ cK0,
    float* __restrict__ y_part, float* __restrict__ m_part,
    float* __restrict__ s_part)
{
    int b = blockIdx.x >> 4, st = blockIdx.x & 15;
    int tid = threadIdx.x, w = tid >> 6, lane = tid & 63;
    int par = lane >> 4, chunk = lane & 15;
    __shared__ float tbuf[8][512];
    __shared__ float s_u[8][SCA];
    __shared__ float s_p[SCA];
    __shared__ float s_cK[FF];
    __shared__ float s_red[8], s_red2[8];
    if (tid < FF) s_cK[tid] = cK[b * FF + tid];
    __syncthreads();

    // tiled: stripe block is 256 rows x 128 cols contiguous
    const __half* base = xh + ((size_t)((b << 4) + st) * 256 + (w << 5) + par) * 128 + (chunk << 3);

    f32x4 hv[8];
#pragma unroll
    for (int r = 0; r < 8; ++r)
        hv[r] = *(const f32x4*)(base + (size_t)(r << 9));    // r*4 rows * 128 halves

    float uc0 = 0, uc1 = 0, uc2 = 0, uc3 = 0, uc4 = 0, uc5 = 0, uc6 = 0, uc7 = 0;
#pragma unroll
    for (int r = 0; r < 8; ++r) {
        int row = (w << 5) + (r << 2) + par;
        H8 u; u.v = hv[r];
        float c = s_cK[row];
        float2 q0 = __half22float2(u.h[0]);
        float2 q1 = __half22float2(u.h[1]);
        float2 q2 = __half22float2(u.h[2]);
        float2 q3 = __half22float2(u.h[3]);
        uc0 = fmaf(c, q0.x, uc0); uc1 = fmaf(c, q0.y, uc1);
        uc2 = fmaf(c, q1.x, uc2); uc3 = fmaf(c, q1.y, uc3);
        uc4 = fmaf(c, q2.x, uc4); uc5 = fmaf(c, q2.y, uc5);
        uc6 = fmaf(c, q3.x, uc6); uc7 = fmaf(c, q3.y, uc7);
    }
    uc0 += __shfl_xor(uc0, 16); uc0 += __shfl_xor(uc0, 32);
    uc1 += __shfl_xor(uc1, 16); uc1 += __shfl_xor(uc1, 32);
    uc2 += __shfl_xor(uc2, 16); uc2 += __shfl_xor(uc2, 32);
    uc3 += __shfl_xor(uc3, 16); uc3 += __shfl_xor(uc3, 32);
    uc4 += __shfl_xor(uc4, 16); uc4 += __shfl_xor(uc4, 32);
    uc5 += __shfl_xor(uc5, 16); uc5 += __shfl_xor(uc5, 32);
    uc6 += __shfl_xor(uc6, 16); uc6 += __shfl_xor(uc6, 32);
    uc7 += __shfl_xor(uc7, 16); uc7 += __shfl_xor(uc7, 32);
    if (par == 0) {
        f32x4 v0 = {uc0, uc1, uc2, uc3}, v1 = {uc4, uc5, uc6, uc7};
        *(f32x4*)&s_u[w][chunk << 3]       = v0;
        *(f32x4*)&s_u[w][(chunk << 3) + 4] = v1;
    }
    __syncthreads();

    const float scale = 0.0625f;
    float uu = -INFINITY;
    if (tid < SCA) {
        int col = (st << 7) + tid;
        if (col < NN) {
            float usum = 0.f;
#pragma unroll
            for (int ww = 0; ww < 8; ++ww) usum += s_u[ww][tid];
            uu = (usum + cK0[b]) * scale;
        }
    }
    float m = uu;
#pragma unroll
    for (int off = 32; off; off >>= 1) m = fmaxf(m, __shfl_xor(m, off));
    if (!lane && w < 2) s_red[w] = m;
    __syncthreads();
    float M = fmaxf(s_red[0], s_red[1]);
    float e = (uu > -INFINITY) ? __expf(uu - M) : 0.f;
    if (tid < SCA) s_p[tid] = e;
    float ssum = e;
#pragma unroll
    for (int off = 32; off; off >>= 1) ssum += __shfl_xor(ssum, off);
    if (!lane && w < 2) s_red2[w] = ssum;
    __syncthreads();
    if (!tid) {
        m_part[(b << 4) + st] = M;
        s_part[(b << 4) + st] = s_red2[0] + s_red2[1];
    }

    f32x4 pv0 = *(const f32x4*)&s_p[chunk << 3];
    f32x4 pv1 = *(const f32x4*)&s_p[(chunk << 3) + 4];
#pragma unroll
    for (int r = 0; r < 8; ++r) {
        H8 u; u.v = hv[r];
        float2 q0 = __half22float2(u.h[0]);
        float2 q1 = __half22float2(u.h[1]);
        float2 q2 = __half22float2(u.h[2]);
        float2 q3 = __half22float2(u.h[3]);
        float a = 0.f;
        a = fmaf(pv0.x, q0.x, a); a = fmaf(pv0.y, q0.y, a);
        a = fmaf(pv0.z, q1.x, a); a = fmaf(pv0.w, q1.y, a);
        a = fmaf(pv1.x, q2.x, a); a = fmaf(pv1.y, q2.y, a);
        a = fmaf(pv1.z, q3.x, a); a = fmaf(pv1.w, q3.y, a);
        tbuf[w][(((r << 2) + par) << 4) + chunk] = a;
    }
    {
        int row = tid >> 1, half = tid & 1;
        const float* srcp = &tbuf[row >> 5][((row & 31) << 4) + (half << 3)];
        f32x4 a0 = *(const f32x4*)srcp;
        f32x4 a1 = *(const f32x4*)(srcp + 4);
        float sm = ((a0.x + a0.y) + (a0.z + a0.w)) + ((a1.x + a1.y) + (a1.z + a1.w));
        sm += __shfl_xor(sm, 1);
        if (!half) y_part[(size_t)((b << 4) + st) * FF + row] = sm;
    }
}

// -------- K4: combine 16 stripe partials -> y -> dense chain (r15 best) --------
__global__ __launch_bounds__(256) void k_dense(
    const float* __restrict__ y_part, const float* __restrict__ m_part,
    const float* __restrict__ s_part,
    const float* __restrict__ Wnode, const float* __restrict__ bnode,
    const float* __restrict__ Wproj, const float* __restrict__ bproj,
    float* __restrict__ cL, float* __restrict__ cL0)
{
    int b = blockIdx.x, tid = threadIdx.x, w = tid >> 6, lane = tid & 63;
    __shared__ float s_y[FF], s_v[FF], s_n[FF], s_b1[FF], s_b2[FF], s_red[FF];

    s_b1[tid] = bnode[FF + tid];
    s_b2[tid] = bproj[tid];
    float M = -INFINITY;
#pragma unroll
    for (int s = 0; s < 16; ++s) M = fmaxf(M, m_part[(b << 4) + s]);
    float S = 0.f, wgt[16];
#pragma unroll
    for (int s = 0; s < 16; ++s) {
        wgt[s] = __expf(m_part[(b << 4) + s] - M);
        S = fmaf(wgt[s], s_part[(b << 4) + s], S);
    }
    float invS = 1.0f / S;
    float acc = 0.f;
#pragma unroll
    for (int s = 0; s < 16; ++s)
        acc = fmaf(wgt[s], y_part[(size_t)((b << 4) + s) * FF + tid], acc);
    s_y[tid] = acc * invS;
    __syncthreads();

    {
        f32x4 yv = *(const f32x4*)&s_y[lane << 2];
        for (int k = 0; k < 64; k += 4) {
            int fb = (w << 6) + k;
            f32x4 w0 = *(const f32x4*)(Wnode + (size_t)(FF + fb) * FF + (lane << 2));
            f32x4 w1 = *(const f32x4*)(Wnode + (size_t)(FF + fb + 1) * FF + (lane << 2));
            f32x4 w2 = *(const f32x4*)(Wnode + (size_t)(FF + fb + 2) * FF + (lane << 2));
            f32x4 w3 = *(const f32x4*)(Wnode + (size_t)(FF + fb + 3) * FF + (lane << 2));
            float p0 = dot4(w0, yv), p1 = dot4(w1, yv), p2 = dot4(w2, yv), p3 = dot4(w3, yv);
#pragma unroll
            for (int off = 32; off; off >>= 1) {
                p0 += __shfl_xor(p0, off);
                p1 += __shfl_xor(p1, off);
                p2 += __shfl_xor(p2, off);
                p3 += __shfl_xor(p3, off);
            }
            if (lane == 0) {
                s_v[fb]     = p0 + s_b1[fb];
                s_v[fb + 1] = p1 + s_b1[fb + 1];
                s_v[fb + 2] = p2 + s_b1[fb + 2];
                s_v[fb + 3] = p3 + s_b1[fb + 3];
            }
        }
    }
    __syncthreads();
    {
        f32x4 vv = *(const f32x4*)&s_v[lane << 2];
        for (int k = 0; k < 64; k += 4) {
            int fb = (w << 6) + k;
            f32x4 w0 = *(const f32x4*)(Wproj + (size_t)fb * FF + (lane << 2));
            f32x4 w1 = *(const f32x4*)(Wproj + (size_t)(fb + 1) * FF + (lane << 2));
            f32x4 w2 = *(const f32x4*)(Wproj + (size_t)(fb + 2) * FF + (lane << 2));
            f32x4 w3 = *(const f32x4*)(Wproj + (size_t)(fb + 3) * FF + (lane << 2));
            float p0 = dot4(w0, vv), p1 = dot4(w1, vv), p2 = dot4(w2, vv), p3 = dot4(w3, vv);
#pragma unroll
            for (int off = 32; off; off >>= 1) {
                p0 += __shfl_xor(p0, off);
                p1 += __shfl_xor(p1, off);
                p2 += __shfl_xor(p2, off);
                p3 += __shfl_xor(p3, off);
            }
            if (lane == 0) {
                s_n[fb]     = p0 + s_b2[fb];
                s_n[fb + 1] = p1 + s_b2[fb + 1];
                s_n[fb + 2] = p2 + s_b2[fb + 2];
                s_n[fb + 3] = p3 + s_b2[fb + 3];
            }
        }
    }
    __syncthreads();
    {
        float a0 = 0, a1 = 0, a2 = 0, a3 = 0, a4 = 0, a5 = 0, a6 = 0, a7 = 0;
        for (int g = 0; g < FF; g += 8) {
            float w0 = Wnode[(size_t)(2 * FF + g + 0) * FF + tid];
            float w1 = Wnode[(size_t)(2 * FF + g + 1) * FF + tid];
            float w2 = Wnode[(size_t)(2 * FF + g + 2) * FF + tid];
            float w3 = Wnode[(size_t)(2 * FF + g + 3) * FF + tid];
            float w4 = Wnode[(size_t)(2 * FF + g + 4) * FF + tid];
            float w5 = Wnode[(size_t)(2 * FF + g + 5) * FF + tid];
            float w6 = Wnode[(size_t)(2 * FF + g + 6) * FF + tid];
            float w7 = Wnode[(size_t)(2 * FF + g + 7) * FF + tid];
            a0 = fmaf(s_n[g + 0], w0, a0); a1 = fmaf(s_n[g + 1], w1, a1);
            a2 = fmaf(s_n[g + 2], w2, a2); a3 = fmaf(s_n[g + 3], w3, a3);
            a4 = fmaf(s_n[g + 4], w4, a4); a5 = fmaf(s_n[g + 5], w5, a5);
            a6 = fmaf(s_n[g + 6], w6, a6); a7 = fmaf(s_n[g + 7], w7, a7);
        }
        cL[b * FF + tid] = ((a0 + a1) + (a2 + a3)) + ((a4 + a5) + (a6 + a7));
    }
    s_red[tid] = s_n[tid] * bnode[2 * FF + tid];
    __syncthreads();
    for (int s = 128; s > 0; s >>= 1) {
        if (tid < s) s_red[tid] += s_red[tid + s];
        __syncthreads();
    }
    if (tid == 0) cL0[b] = s_red[0];
}

// -------- K5: logits + tanh, register tile over TILED xh (mirror of attn pass 1) --------
__global__ __launch_bounds__(512) void k_logits(const __half* __restrict__ xh,
                                                const float* __restrict__ cL,
                                                const float* __restrict__ cL0,
                                                float* __restrict__ out)
{
    int b = blockIdx.x >> 4, st = blockIdx.x & 15;
    int tid = threadIdx.x, w = tid >> 6, lane = tid & 63;
    int par = lane >> 4, chunk = lane & 15;
    __shared__ float s_cL[FF];
    __shared__ float s_acc[8][SCA];
    if (tid < FF) s_cL[tid] = cL[b * FF + tid];
    __syncthreads();

    const __half* base = xh + ((size_t)((b << 4) + st) * 256 + (w << 5) + par) * 128 + (chunk << 3);
    f32x4 hv[8];
#pragma unroll
    for (int r = 0; r < 8; ++r)
        hv[r] = *(const f32x4*)(base + (size_t)(r << 9));

    float uc0 = 0, uc1 = 0, uc2 = 0, uc3 = 0, uc4 = 0, uc5 = 0, uc6 = 0, uc7 = 0;
#pragma unroll
    for (int r = 0; r < 8; ++r) {
        int row = (w << 5) + (r << 2) + par;
        H8 u; u.v = hv[r];
        float c = s_cL[row];
        float2 q0 = __half22float2(u.h[0]);
        float2 q1 = __half22float2(u.h[1]);
        float2 q2 = __half22float2(u.h[2]);
        float2 q3 = __half22float2(u.h[3]);
        uc0 = fmaf(c, q0.x, uc0); uc1 = fmaf(c, q0.y, uc1);
        uc2 = fmaf(c, q1.x, uc2); uc3 = fmaf(c, q1.y, uc3);
        uc4 = fmaf(c, q2.x, uc4); uc5 = fmaf(c, q2.y, uc5);
        uc6 = fmaf(c, q3.x, uc6); uc7 = fmaf(c, q3.y, uc7);
    }
    uc0 += __shfl_xor(uc0, 16); uc0 += __shfl_xor(uc0, 32);
    uc1 += __shfl_xor(uc1, 16); uc1 += __shfl_xor(uc1, 32);
    uc2 += __shfl_xor(uc2, 16); uc2 += __shfl_xor(uc2, 32);
    uc3 += __shfl_xor(uc3, 16); uc3 += __shfl_xor(uc3, 32);
    uc4 += __shfl_xor(uc4, 16); uc4 += __shfl_xor(uc4, 32);
    uc5 += __shfl_xor(uc5, 16); uc5 += __shfl_xor(uc5, 32);
    uc6 += __shfl_xor(uc6, 16); uc6 += __shfl_xor(uc6, 32);
    uc7 += __shfl_xor(uc7, 16); uc7 += __shfl_xor(uc7, 32);
    if (par == 0) {
        f32x4 v0 = {uc0, uc1, uc2, uc3}, v1 = {uc4, uc5, uc6, uc7};
        *(f32x4*)&s_acc[w][chunk << 3]       = v0;
        *(f32x4*)&s_acc[w][(chunk << 3) + 4] = v1;
    }
    __syncthreads();
    if (tid < SCA) {
        int col = (st << 7) + tid;
        if (col < NN) {
            float t = 0.f;
#pragma unroll
            for (int ww = 0; ww < 8; ++ww) t += s_acc[ww][tid];
            out[(size_t)b * NN + col] = tanhf((t + cL0[b]) * 0.0625f) * 10.f;
        }
    }
}

extern "C" void kernel_launch(void* const* d_in, const int* in_sizes, int n_in,
                              void* d_out, int out_size, void* d_ws, size_t ws_size,
                              hipStream_t stream) {
    const float* x     = (const float*)d_in[0];
    const int*   lc    = (const int*)d_in[1];
    const float* Wg    = (const float*)d_in[2];
    const float* bg    = (const float*)d_in[3];
    const float* Wnode = (const float*)d_in[4];
    const float* bnode = (const float*)d_in[5];
    const float* Wlc   = (const float*)d_in[6];
    const float* blc   = (const float*)d_in[7];
    const float* Wproj = (const float*)d_in[8];
    const float* bproj = (const float*)d_in[9];
    float* out = (float*)d_out;

    float* ws     = (float*)d_ws;
    float* glb    = ws + 0;          // B*F
    float* xg     = ws + 32768;      // B*F*2
    float* cK     = ws + 98304;      // B*F
    float* cK0    = ws + 131072;     // B
    float* m_part = ws + 132096;     // B*16
    float* s_part = ws + 134144;     // B*16
    float* cL     = ws + 136192;     // B*F
    float* cL0    = ws + 168960;     // B
    float* y_part = ws + 169984;     // B*16*F
    __half* xh    = (__half*)(ws + (2 << 20));  // tiled, 128 MB at 8 MB offset

    k_convmax<<<BB * FF / 4, 256, 0, stream>>>(x, lc, xh, glb, xg);
    k_prep   <<<BB, 256, 0, stream>>>(xg, glb, Wg, bg, Wnode, bnode, Wlc, blc, cK, cK0);
    k_attn   <<<BB * SWA, 512, 0, stream>>>(xh, cK, cK0, y_part, m_part, s_part);
    k_dense  <<<BB, 256, 0, stream>>>(y_part, m_part, s_part, Wnode, bnode, Wproj, bproj, cL, cL0);
    k_logits <<<BB * SWA, 512, 0, stream>>>(xh, cL, cL0, out);
}